// Round 1
// baseline (190.246 us; speedup 1.0000x reference)
//
#include <hip/hip_runtime.h>
#include <stdint.h>

typedef __attribute__((ext_vector_type(4))) int i32x4;

__device__ inline float wave_max(float v){ for(int o=32;o;o>>=1) v=fmaxf(v,__shfl_xor(v,o)); return v; }
__device__ inline float wave_min(float v){ for(int o=32;o;o>>=1) v=fminf(v,__shfl_xor(v,o)); return v; }
__device__ inline int   wave_sum(int v){ for(int o=32;o;o>>=1) v+=__shfl_xor(v,o); return v; }

__device__ inline void gload16(const void* g, void* l){
  __builtin_amdgcn_global_load_lds((const __attribute__((address_space(1))) char*)g,
                                   (__attribute__((address_space(3))) char*)l, 16, 0, 0);
}

__global__ void k_init(uint32_t* xmax_bits){ *xmax_bits = 0u; }

__global__ void k_xmax(const float* __restrict__ x, long long n4, uint32_t* xmax_bits){
  long long i = (long long)blockIdx.x*blockDim.x + threadIdx.x;
  long long stride = (long long)gridDim.x*blockDim.x;
  const float4* x4 = (const float4*)x;
  float m = 0.f;
  for(; i < n4; i += stride){
    float4 v = x4[i];
    m = fmaxf(m, fmaxf(fmaxf(v.x,v.y),fmaxf(v.z,v.w)));
  }
  m = wave_max(m);
  if((threadIdx.x & 63) == 0) atomicMax(xmax_bits, __float_as_uint(m));
}

// one block (256 thr) per output channel row; din must be 2048
__global__ void k_wstat(const float* __restrict__ w, const float* __restrict__ bias,
                        const int* __restrict__ wbit, const uint32_t* __restrict__ xmax_bits,
                        float* __restrict__ scale_w, float* __restrict__ zp_w,
                        int* __restrict__ cint, char* __restrict__ qw, int din){
  int row = blockIdx.x, tid = threadIdx.x;
  int lane = tid & 63, wid = tid >> 6;
  const float4* wr4 = (const float4*)(w + (long long)row*din);
  float4 a = wr4[tid*2], b = wr4[tid*2+1];
  float v[8] = {a.x,a.y,a.z,a.w,b.x,b.y,b.z,b.w};
  float mn = v[0], mx = v[0];
  for(int j=1;j<8;j++){ mn=fminf(mn,v[j]); mx=fmaxf(mx,v[j]); }
  float wmn = wave_min(mn), wmx = wave_max(mx);
  __shared__ float smn[4], smx[4];
  __shared__ float s_sw, s_zp; __shared__ int s_qb;
  if(lane==0){ smn[wid]=wmn; smx[wid]=wmx; }
  __syncthreads();
  if(tid==0){
    float fmn = fminf(fminf(smn[0],smn[1]),fminf(smn[2],smn[3]));
    float fmx = fmaxf(fmaxf(smx[0],smx[1]),fmaxf(smx[2],smx[3]));
    int n = 1 << *wbit;
    float nm1 = (float)(n-1);
    float xmax = __uint_as_float(*xmax_bits);
    float sx = __fdiv_rn(nm1, fmaxf(xmax, 1e-8f));
    float rng = __fsub_rn(fmx, fmn);
    float sw = __fdiv_rn(nm1, fmaxf(rng, 1e-8f));
    float zp = __fmul_rn(sw, fmn);
    float qbf = rintf(__fmul_rn(__fmul_rn(bias[row], sw), sx));
    qbf = fminf(fmaxf(qbf, -(float)(n+1)), (float)n);
    s_sw = sw; s_zp = zp; s_qb = (int)qbf;
    scale_w[row] = sw; zp_w[row] = zp;
  }
  __syncthreads();
  float sw = s_sw, zp = s_zp;
  int qsum = 0; uint32_t lo = 0, hi = 0;
  for(int j=0;j<8;j++){
    int q = (int)rintf(__fsub_rn(__fmul_rn(sw, v[j]), zp));   // exact replication, no fma
    qsum += q;
    uint32_t u = (uint32_t)((q - 128) & 0xff);
    if(j<4) lo |= u << (8*j); else hi |= u << (8*(j-4));
  }
  uint32_t* qrow = (uint32_t*)(qw + (long long)row*din);
  qrow[tid*2] = lo; qrow[tid*2+1] = hi;
  int wsum = wave_sum(qsum);
  __shared__ int ssum[4];
  if(lane==0) ssum[wid] = wsum;
  __syncthreads();
  if(tid==0){
    int Sb = ssum[0]+ssum[1]+ssum[2]+ssum[3];
    cint[row] = 128*Sb - 128*128*din + s_qb;
  }
}

// one block (256 thr) per token row
__global__ void k_xquant(const float* __restrict__ x, const int* __restrict__ wbit,
                         const uint32_t* __restrict__ xmax_bits,
                         char* __restrict__ qx, int* __restrict__ Sa, int din){
  int row = blockIdx.x, tid = threadIdx.x;
  int lane = tid & 63, wid = tid >> 6;
  int n = 1 << *wbit;
  float nm1 = (float)(n-1);
  float sx = __fdiv_rn(nm1, fmaxf(__uint_as_float(*xmax_bits), 1e-8f));
  const float4* xr4 = (const float4*)(x + (long long)row*din);
  float4 a = xr4[tid*2], b = xr4[tid*2+1];
  float v[8] = {a.x,a.y,a.z,a.w,b.x,b.y,b.z,b.w};
  int qsum = 0; uint32_t lo = 0, hi = 0;
  for(int j=0;j<8;j++){
    int q = (int)rintf(__fmul_rn(sx, v[j]));
    qsum += q;
    uint32_t u = (uint32_t)((q - 128) & 0xff);
    if(j<4) lo |= u << (8*j); else hi |= u << (8*(j-4));
  }
  uint32_t* qrow = (uint32_t*)(qx + (long long)row*din);
  qrow[tid*2] = lo; qrow[tid*2+1] = hi;
  int wsum = wave_sum(qsum);
  __shared__ int ssum[4];
  if(lane==0) ssum[wid] = wsum;
  __syncthreads();
  if(tid==0) Sa[row] = ssum[0]+ssum[1]+ssum[2]+ssum[3];
}

// 128x128 tile, BK=128 i8, 4 waves (2x2 of 64x64), mfma_i32_16x16x64_i8
__global__ __launch_bounds__(256) void k_gemm(
    const char* __restrict__ qx, const char* __restrict__ qw,
    const int* __restrict__ Sa, const int* __restrict__ cint,
    const float* __restrict__ scale_w, const float* __restrict__ zp_w,
    const int* __restrict__ wbit, const uint32_t* __restrict__ xmax_bits,
    float* __restrict__ out, int T, int dout, int din){
  __shared__ __align__(16) char As[128*128];
  __shared__ __align__(16) char Bs[128*128];
  int tid = threadIdx.x, lane = tid & 63, wid = tid >> 6;
  int tileN = blockIdx.x, tileM = blockIdx.y;
  const char* aSrc = qx + (long long)tileM*128*din;
  const char* bSrc = qw + (long long)tileN*128*din;
  int srow = tid >> 3;          // 0..31
  int scol = (tid & 7) * 16;    // 0..112
  i32x4 acc[4][4] = {};
  int nk = din / 128;
  int wr = (wid >> 1) * 64, wc = (wid & 1) * 64;
  for(int kt = 0; kt < nk; ++kt){
    __syncthreads();
    long long koff = (long long)kt*128 + scol;
    for(int j=0;j<4;j++){
      gload16(aSrc + (long long)(srow + j*32)*din + koff, As + tid*16 + j*4096);
      gload16(bSrc + (long long)(srow + j*32)*din + koff, Bs + tid*16 + j*4096);
    }
    __syncthreads();
    for(int kk = 0; kk < 128; kk += 64){
      int ko = kk + (lane >> 4) * 16;
      i32x4 af[4], bf[4];
      for(int mi=0;mi<4;mi++) af[mi] = *(const i32x4*)(As + (wr + mi*16 + (lane&15))*128 + ko);
      for(int ni=0;ni<4;ni++) bf[ni] = *(const i32x4*)(Bs + (wc + ni*16 + (lane&15))*128 + ko);
      for(int mi=0;mi<4;mi++)
        for(int ni=0;ni<4;ni++)
          acc[mi][ni] = __builtin_amdgcn_mfma_i32_16x16x64_i8(af[mi], bf[ni], acc[mi][ni], 0, 0, 0);
    }
  }
  // epilogue: out = ((dot_s +128*Sa +Cint) + zp_w*Sa) / sx / sw
  int n = 1 << *wbit;
  float nm1 = (float)(n-1);
  float sx = __fdiv_rn(nm1, fmaxf(__uint_as_float(*xmax_bits), 1e-8f));
  int row0 = tileM*128 + wr + ((lane >> 4) * 4);
  int col0 = tileN*128 + wc + (lane & 15);
  for(int mi=0;mi<4;mi++){
    for(int ni=0;ni<4;ni++){
      int o = col0 + ni*16;
      float swo = scale_w[o], zpo = zp_w[o];
      int ci = cint[o];
      for(int r=0;r<4;r++){
        int t = row0 + mi*16 + r;
        int sa = Sa[t];
        float val = (float)(acc[mi][ni][r] + 128*sa + ci) + zpo * (float)sa;
        out[(long long)t*dout + o] = __fdiv_rn(__fdiv_rn(val, sx), swo);
      }
    }
  }
}

extern "C" void kernel_launch(void* const* d_in, const int* in_sizes, int n_in,
                              void* d_out, int out_size, void* d_ws, size_t ws_size,
                              hipStream_t stream){
  const float* x    = (const float*)d_in[0];
  const float* w    = (const float*)d_in[1];
  const float* bias = (const float*)d_in[2];
  const int*   wbit = (const int*)d_in[3];
  int dout = in_sizes[2];
  int din  = in_sizes[1] / dout;
  int T    = in_sizes[0] / din;

  char* ws = (char*)d_ws;
  uint32_t* xmax_bits = (uint32_t*)ws;
  size_t off = 256;
  float* scale_w = (float*)(ws + off); off += 4*(size_t)dout;
  float* zp_w    = (float*)(ws + off); off += 4*(size_t)dout;
  int*   cint    = (int*)(ws + off);   off += 4*(size_t)dout;
  int*   Sa      = (int*)(ws + off);   off += 4*(size_t)T;
  off = (off + 255) & ~(size_t)255;
  char*  qw      = ws + off;           off += (size_t)dout*din;
  char*  qx      = ws + off;           off += (size_t)T*din;

  k_init<<<1, 1, 0, stream>>>(xmax_bits);
  long long n4 = (long long)T*din/4;
  k_xmax<<<2048, 256, 0, stream>>>(x, n4, xmax_bits);
  k_wstat<<<dout, 256, 0, stream>>>(w, bias, wbit, xmax_bits, scale_w, zp_w, cint, qw, din);
  k_xquant<<<T, 256, 0, stream>>>(x, wbit, xmax_bits, qx, Sa, din);
  dim3 grid(dout/128, T/128);
  k_gemm<<<grid, 256, 0, stream>>>(qx, qw, Sa, cint, scale_w, zp_w, wbit, xmax_bits,
                                   (float*)d_out, T, dout, din);
}

// Round 2
// 99.605 us; speedup vs baseline: 1.9100x; 1.9100x over previous
//
#include <hip/hip_runtime.h>
#include <stdint.h>

typedef __attribute__((ext_vector_type(4))) int i32x4;

__device__ inline float wave_max(float v){ for(int o=32;o;o>>=1) v=fmaxf(v,__shfl_xor(v,o)); return v; }
__device__ inline float wave_min(float v){ for(int o=32;o;o>>=1) v=fminf(v,__shfl_xor(v,o)); return v; }
__device__ inline int   wave_sum(int v){ for(int o=32;o;o>>=1) v+=__shfl_xor(v,o); return v; }

__device__ inline void gload16(const void* g, void* l){
  __builtin_amdgcn_global_load_lds((const __attribute__((address_space(1))) char*)g,
                                   (__attribute__((address_space(3))) char*)l, 16, 0, 0);
}

// stage 1: per-block max -> partials[blockIdx.x]  (no atomics)
__global__ void k_xmax_partial(const float* __restrict__ x, long long n4,
                               float* __restrict__ partials){
  long long i = (long long)blockIdx.x*blockDim.x + threadIdx.x;
  long long stride = (long long)gridDim.x*blockDim.x;
  const float4* x4 = (const float4*)x;
  float m = 0.f;
  for(; i < n4; i += stride){
    float4 v = x4[i];
    m = fmaxf(m, fmaxf(fmaxf(v.x,v.y),fmaxf(v.z,v.w)));
  }
  m = wave_max(m);
  __shared__ float sm[4];
  int lane = threadIdx.x & 63, wid = threadIdx.x >> 6;
  if(lane==0) sm[wid] = m;
  __syncthreads();
  if(threadIdx.x==0)
    partials[blockIdx.x] = fmaxf(fmaxf(sm[0],sm[1]),fmaxf(sm[2],sm[3]));
}

// stage 2: one block reduces nPart partials
__global__ void k_xmax_final(const float* __restrict__ partials, int nPart,
                             uint32_t* __restrict__ xmax_bits){
  float m = 0.f;
  for(int i = threadIdx.x; i < nPart; i += 256) m = fmaxf(m, partials[i]);
  m = wave_max(m);
  __shared__ float sm[4];
  int lane = threadIdx.x & 63, wid = threadIdx.x >> 6;
  if(lane==0) sm[wid] = m;
  __syncthreads();
  if(threadIdx.x==0)
    *xmax_bits = __float_as_uint(fmaxf(fmaxf(sm[0],sm[1]),fmaxf(sm[2],sm[3])));
}

// one block (256 thr) per output channel row; din must be 2048
__global__ void k_wstat(const float* __restrict__ w, const float* __restrict__ bias,
                        const int* __restrict__ wbit, const uint32_t* __restrict__ xmax_bits,
                        float* __restrict__ scale_w, float* __restrict__ zp_w,
                        int* __restrict__ cint, char* __restrict__ qw, int din){
  int row = blockIdx.x, tid = threadIdx.x;
  int lane = tid & 63, wid = tid >> 6;
  const float4* wr4 = (const float4*)(w + (long long)row*din);
  float4 a = wr4[tid*2], b = wr4[tid*2+1];
  float v[8] = {a.x,a.y,a.z,a.w,b.x,b.y,b.z,b.w};
  float mn = v[0], mx = v[0];
  for(int j=1;j<8;j++){ mn=fminf(mn,v[j]); mx=fmaxf(mx,v[j]); }
  float wmn = wave_min(mn), wmx = wave_max(mx);
  __shared__ float smn[4], smx[4];
  __shared__ float s_sw, s_zp; __shared__ int s_qb;
  if(lane==0){ smn[wid]=wmn; smx[wid]=wmx; }
  __syncthreads();
  if(tid==0){
    float fmn = fminf(fminf(smn[0],smn[1]),fminf(smn[2],smn[3]));
    float fmx = fmaxf(fmaxf(smx[0],smx[1]),fmaxf(smx[2],smx[3]));
    int n = 1 << *wbit;
    float nm1 = (float)(n-1);
    float xmax = __uint_as_float(*xmax_bits);
    float sx = __fdiv_rn(nm1, fmaxf(xmax, 1e-8f));
    float rng = __fsub_rn(fmx, fmn);
    float sw = __fdiv_rn(nm1, fmaxf(rng, 1e-8f));
    float zp = __fmul_rn(sw, fmn);
    float qbf = rintf(__fmul_rn(__fmul_rn(bias[row], sw), sx));
    qbf = fminf(fmaxf(qbf, -(float)(n+1)), (float)n);
    s_sw = sw; s_zp = zp; s_qb = (int)qbf;
    scale_w[row] = sw; zp_w[row] = zp;
  }
  __syncthreads();
  float sw = s_sw, zp = s_zp;
  int qsum = 0; uint32_t lo = 0, hi = 0;
  for(int j=0;j<8;j++){
    int q = (int)rintf(__fsub_rn(__fmul_rn(sw, v[j]), zp));   // exact replication, no fma
    qsum += q;
    uint32_t u = (uint32_t)((q - 128) & 0xff);
    if(j<4) lo |= u << (8*j); else hi |= u << (8*(j-4));
  }
  uint32_t* qrow = (uint32_t*)(qw + (long long)row*din);
  qrow[tid*2] = lo; qrow[tid*2+1] = hi;
  int wsum = wave_sum(qsum);
  __shared__ int ssum[4];
  if(lane==0) ssum[wid] = wsum;
  __syncthreads();
  if(tid==0){
    int Sb = ssum[0]+ssum[1]+ssum[2]+ssum[3];
    cint[row] = 128*Sb - 128*128*din + s_qb;
  }
}

// one block (256 thr) per token row
__global__ void k_xquant(const float* __restrict__ x, const int* __restrict__ wbit,
                         const uint32_t* __restrict__ xmax_bits,
                         char* __restrict__ qx, int* __restrict__ Sa, int din){
  int row = blockIdx.x, tid = threadIdx.x;
  int lane = tid & 63, wid = tid >> 6;
  int n = 1 << *wbit;
  float nm1 = (float)(n-1);
  float sx = __fdiv_rn(nm1, fmaxf(__uint_as_float(*xmax_bits), 1e-8f));
  const float4* xr4 = (const float4*)(x + (long long)row*din);
  float4 a = xr4[tid*2], b = xr4[tid*2+1];
  float v[8] = {a.x,a.y,a.z,a.w,b.x,b.y,b.z,b.w};
  int qsum = 0; uint32_t lo = 0, hi = 0;
  for(int j=0;j<8;j++){
    int q = (int)rintf(__fmul_rn(sx, v[j]));
    qsum += q;
    uint32_t u = (uint32_t)((q - 128) & 0xff);
    if(j<4) lo |= u << (8*j); else hi |= u << (8*(j-4));
  }
  uint32_t* qrow = (uint32_t*)(qx + (long long)row*din);
  qrow[tid*2] = lo; qrow[tid*2+1] = hi;
  int wsum = wave_sum(qsum);
  __shared__ int ssum[4];
  if(lane==0) ssum[wid] = wsum;
  __syncthreads();
  if(tid==0) Sa[row] = ssum[0]+ssum[1]+ssum[2]+ssum[3];
}

// 128x128 tile, BK=128 i8, 4 waves (2x2 of 64x64), mfma_i32_16x16x64_i8
__global__ __launch_bounds__(256) void k_gemm(
    const char* __restrict__ qx, const char* __restrict__ qw,
    const int* __restrict__ Sa, const int* __restrict__ cint,
    const float* __restrict__ scale_w, const float* __restrict__ zp_w,
    const int* __restrict__ wbit, const uint32_t* __restrict__ xmax_bits,
    float* __restrict__ out, int T, int dout, int din){
  __shared__ __align__(16) char As[128*128];
  __shared__ __align__(16) char Bs[128*128];
  int tid = threadIdx.x, lane = tid & 63, wid = tid >> 6;
  int tileN = blockIdx.x, tileM = blockIdx.y;
  const char* aSrc = qx + (long long)tileM*128*din;
  const char* bSrc = qw + (long long)tileN*128*din;
  int srow = tid >> 3;          // 0..31
  int scol = (tid & 7) * 16;    // 0..112
  i32x4 acc[4][4] = {};
  int nk = din / 128;
  int wr = (wid >> 1) * 64, wc = (wid & 1) * 64;
  for(int kt = 0; kt < nk; ++kt){
    __syncthreads();
    long long koff = (long long)kt*128 + scol;
    for(int j=0;j<4;j++){
      gload16(aSrc + (long long)(srow + j*32)*din + koff, As + tid*16 + j*4096);
      gload16(bSrc + (long long)(srow + j*32)*din + koff, Bs + tid*16 + j*4096);
    }
    __syncthreads();
    for(int kk = 0; kk < 128; kk += 64){
      int ko = kk + (lane >> 4) * 16;
      i32x4 af[4], bf[4];
      for(int mi=0;mi<4;mi++) af[mi] = *(const i32x4*)(As + (wr + mi*16 + (lane&15))*128 + ko);
      for(int ni=0;ni<4;ni++) bf[ni] = *(const i32x4*)(Bs + (wc + ni*16 + (lane&15))*128 + ko);
      for(int mi=0;mi<4;mi++)
        for(int ni=0;ni<4;ni++)
          acc[mi][ni] = __builtin_amdgcn_mfma_i32_16x16x64_i8(af[mi], bf[ni], acc[mi][ni], 0, 0, 0);
    }
  }
  // epilogue: out = ((dot_s +128*Sa +Cint) + zp_w*Sa) / sx / sw
  int n = 1 << *wbit;
  float nm1 = (float)(n-1);
  float sx = __fdiv_rn(nm1, fmaxf(__uint_as_float(*xmax_bits), 1e-8f));
  int row0 = tileM*128 + wr + ((lane >> 4) * 4);
  int col0 = tileN*128 + wc + (lane & 15);
  for(int mi=0;mi<4;mi++){
    for(int ni=0;ni<4;ni++){
      int o = col0 + ni*16;
      float swo = scale_w[o], zpo = zp_w[o];
      int ci = cint[o];
      for(int r=0;r<4;r++){
        int t = row0 + mi*16 + r;
        int sa = Sa[t];
        float val = (float)(acc[mi][ni][r] + 128*sa + ci) + zpo * (float)sa;
        out[(long long)t*dout + o] = __fdiv_rn(__fdiv_rn(val, sx), swo);
      }
    }
  }
}

extern "C" void kernel_launch(void* const* d_in, const int* in_sizes, int n_in,
                              void* d_out, int out_size, void* d_ws, size_t ws_size,
                              hipStream_t stream){
  const float* x    = (const float*)d_in[0];
  const float* w    = (const float*)d_in[1];
  const float* bias = (const float*)d_in[2];
  const int*   wbit = (const int*)d_in[3];
  int dout = in_sizes[2];
  int din  = in_sizes[1] / dout;
  int T    = in_sizes[0] / din;

  const int NPART = 2048;
  char* ws = (char*)d_ws;
  uint32_t* xmax_bits = (uint32_t*)ws;
  size_t off = 256;
  float* partials = (float*)(ws + off); off += 4*(size_t)NPART;
  float* scale_w = (float*)(ws + off); off += 4*(size_t)dout;
  float* zp_w    = (float*)(ws + off); off += 4*(size_t)dout;
  int*   cint    = (int*)(ws + off);   off += 4*(size_t)dout;
  int*   Sa      = (int*)(ws + off);   off += 4*(size_t)T;
  off = (off + 255) & ~(size_t)255;
  char*  qw      = ws + off;           off += (size_t)dout*din;
  char*  qx      = ws + off;           off += (size_t)T*din;

  long long n4 = (long long)T*din/4;
  k_xmax_partial<<<NPART, 256, 0, stream>>>(x, n4, partials);
  k_xmax_final<<<1, 256, 0, stream>>>(partials, NPART, xmax_bits);
  k_wstat<<<dout, 256, 0, stream>>>(w, bias, wbit, xmax_bits, scale_w, zp_w, cint, qw, din);
  k_xquant<<<T, 256, 0, stream>>>(x, wbit, xmax_bits, qx, Sa, din);
  dim3 grid(dout/128, T/128);
  k_gemm<<<grid, 256, 0, stream>>>(qx, qw, Sa, cint, scale_w, zp_w, wbit, xmax_bits,
                                   (float*)d_out, T, dout, din);
}

// Round 3
// 81.010 us; speedup vs baseline: 2.3484x; 1.2295x over previous
//
#include <hip/hip_runtime.h>
#include <stdint.h>

typedef __attribute__((ext_vector_type(4))) int i32x4;

__device__ inline float wave_max(float v){ for(int o=32;o;o>>=1) v=fmaxf(v,__shfl_xor(v,o)); return v; }
__device__ inline float wave_min(float v){ for(int o=32;o;o>>=1) v=fminf(v,__shfl_xor(v,o)); return v; }
__device__ inline int   wave_sum(int v){ for(int o=32;o;o>>=1) v+=__shfl_xor(v,o); return v; }

__device__ inline void gload16(const void* g, void* l){
  __builtin_amdgcn_global_load_lds((const __attribute__((address_space(1))) char*)g,
                                   (__attribute__((address_space(3))) char*)l, 16, 0, 0);
}

// stage 1: per-block max -> partials[blockIdx.x]  (no atomics)
__global__ void k_xmax_partial(const float* __restrict__ x, long long n4,
                               float* __restrict__ partials){
  long long i = (long long)blockIdx.x*blockDim.x + threadIdx.x;
  long long stride = (long long)gridDim.x*blockDim.x;
  const float4* x4 = (const float4*)x;
  float m = 0.f;
  for(; i < n4; i += stride){
    float4 v = x4[i];
    m = fmaxf(m, fmaxf(fmaxf(v.x,v.y),fmaxf(v.z,v.w)));
  }
  m = wave_max(m);
  __shared__ float sm[4];
  int lane = threadIdx.x & 63, wid = threadIdx.x >> 6;
  if(lane==0) sm[wid] = m;
  __syncthreads();
  if(threadIdx.x==0)
    partials[blockIdx.x] = fmaxf(fmaxf(sm[0],sm[1]),fmaxf(sm[2],sm[3]));
}

// stage 2: one block reduces nPart partials
__global__ void k_xmax_final(const float* __restrict__ partials, int nPart,
                             uint32_t* __restrict__ xmax_bits){
  float m = 0.f;
  for(int i = threadIdx.x; i < nPart; i += 256) m = fmaxf(m, partials[i]);
  m = wave_max(m);
  __shared__ float sm[4];
  int lane = threadIdx.x & 63, wid = threadIdx.x >> 6;
  if(lane==0) sm[wid] = m;
  __syncthreads();
  if(threadIdx.x==0)
    *xmax_bits = __float_as_uint(fmaxf(fmaxf(sm[0],sm[1]),fmaxf(sm[2],sm[3])));
}

// one block (256 thr) per output channel row; din must be 2048
__global__ void k_wstat(const float* __restrict__ w, const float* __restrict__ bias,
                        const int* __restrict__ wbit, const uint32_t* __restrict__ xmax_bits,
                        float* __restrict__ scale_w, float* __restrict__ zp_w,
                        float* __restrict__ winv,
                        int* __restrict__ cint, char* __restrict__ qw, int din){
  int row = blockIdx.x, tid = threadIdx.x;
  int lane = tid & 63, wid = tid >> 6;
  const float4* wr4 = (const float4*)(w + (long long)row*din);
  float4 a = wr4[tid*2], b = wr4[tid*2+1];
  float v[8] = {a.x,a.y,a.z,a.w,b.x,b.y,b.z,b.w};
  float mn = v[0], mx = v[0];
  for(int j=1;j<8;j++){ mn=fminf(mn,v[j]); mx=fmaxf(mx,v[j]); }
  float wmn = wave_min(mn), wmx = wave_max(mx);
  __shared__ float smn[4], smx[4];
  __shared__ float s_sw, s_zp; __shared__ int s_qb;
  if(lane==0){ smn[wid]=wmn; smx[wid]=wmx; }
  __syncthreads();
  if(tid==0){
    float fmn = fminf(fminf(smn[0],smn[1]),fminf(smn[2],smn[3]));
    float fmx = fmaxf(fmaxf(smx[0],smx[1]),fmaxf(smx[2],smx[3]));
    int n = 1 << *wbit;
    float nm1 = (float)(n-1);
    float xmax = __uint_as_float(*xmax_bits);
    float sx = __fdiv_rn(nm1, fmaxf(xmax, 1e-8f));
    float rng = __fsub_rn(fmx, fmn);
    float rngc = fmaxf(rng, 1e-8f);
    float sw = __fdiv_rn(nm1, rngc);
    float zp = __fmul_rn(sw, fmn);
    float qbf = rintf(__fmul_rn(__fmul_rn(bias[row], sw), sx));
    qbf = fminf(fmaxf(qbf, -(float)(n+1)), (float)n);
    s_sw = sw; s_zp = zp; s_qb = (int)qbf;
    scale_w[row] = sw; zp_w[row] = zp;
    winv[row] = __fdiv_rn(rngc, nm1);     // 1/scale_w, one rounding
  }
  __syncthreads();
  float sw = s_sw, zp = s_zp;
  int qsum = 0; uint32_t lo = 0, hi = 0;
  for(int j=0;j<8;j++){
    int q = (int)rintf(__fsub_rn(__fmul_rn(sw, v[j]), zp));   // exact replication, no fma
    qsum += q;
    uint32_t u = (uint32_t)((q - 128) & 0xff);
    if(j<4) lo |= u << (8*j); else hi |= u << (8*(j-4));
  }
  uint32_t* qrow = (uint32_t*)(qw + (long long)row*din);
  qrow[tid*2] = lo; qrow[tid*2+1] = hi;
  int wsum = wave_sum(qsum);
  __shared__ int ssum[4];
  if(lane==0) ssum[wid] = wsum;
  __syncthreads();
  if(tid==0){
    int Sb = ssum[0]+ssum[1]+ssum[2]+ssum[3];
    cint[row] = 128*Sb - 128*128*din + s_qb;
  }
}

// one block (256 thr) per token row
__global__ void k_xquant(const float* __restrict__ x, const int* __restrict__ wbit,
                         const uint32_t* __restrict__ xmax_bits,
                         char* __restrict__ qx, int* __restrict__ Sa, int din){
  int row = blockIdx.x, tid = threadIdx.x;
  int lane = tid & 63, wid = tid >> 6;
  int n = 1 << *wbit;
  float nm1 = (float)(n-1);
  float sx = __fdiv_rn(nm1, fmaxf(__uint_as_float(*xmax_bits), 1e-8f));
  const float4* xr4 = (const float4*)(x + (long long)row*din);
  float4 a = xr4[tid*2], b = xr4[tid*2+1];
  float v[8] = {a.x,a.y,a.z,a.w,b.x,b.y,b.z,b.w};
  int qsum = 0; uint32_t lo = 0, hi = 0;
  for(int j=0;j<8;j++){
    int q = (int)rintf(__fmul_rn(sx, v[j]));
    qsum += q;
    uint32_t u = (uint32_t)((q - 128) & 0xff);
    if(j<4) lo |= u << (8*j); else hi |= u << (8*(j-4));
  }
  uint32_t* qrow = (uint32_t*)(qx + (long long)row*din);
  qrow[tid*2] = lo; qrow[tid*2+1] = hi;
  int wsum = wave_sum(qsum);
  __shared__ int ssum[4];
  if(lane==0) ssum[wid] = wsum;
  __syncthreads();
  if(tid==0) Sa[row] = ssum[0]+ssum[1]+ssum[2]+ssum[3];
}

// ===================== 256x256 tri-buffered counted-vmcnt i8 GEMM =====================
// BM=BN=256, BK=64 (bytes). 8 waves (2Mx4N), per-wave 128x64 out.
// LDS: 3 slots x (A 16K + B 16K) = 96 KiB. Tile t computed from slot t%3;
// tile t+2 staged (4 gload16/thread) during tile t into slot (t+2)%3 -> race-free.
// Boundary wait: vmcnt(4) (tile t+2's 4 loads stay in flight), never 0 in main loop.
// LDS swizzle: 16B-chunk c2 ^= (row>>1)&3, applied to global SOURCE (write side,
// rule #21) and on ds_read -> 2-way (free) instead of 16-way bank conflict.
#define TILE_BYTES 16384

__global__ __launch_bounds__(512, 2) void k_gemm(
    const char* __restrict__ qx, const char* __restrict__ qw,
    const int* __restrict__ Sa, const int* __restrict__ cint,
    const float* __restrict__ winv, const float* __restrict__ zp_w,
    const int* __restrict__ wbit, const uint32_t* __restrict__ xmax_bits,
    float* __restrict__ out, int T, int dout, int din){
  extern __shared__ char lds[];   // 6*TILE_BYTES: A slots [0..3), B slots [3..6)
  const int tid = threadIdx.x, lane = tid & 63, wid = tid >> 6;
  const int wr = wid >> 2, wc = wid & 3;
  const int tileN = blockIdx.x, tileM = blockIdx.y;

  // ---- staging constants (2 chunk-loads per operand per K-tile) ----
  // chunk idx: j*512+tid; row=idx>>2, c2=idx&3; source pre-swizzled: c2^((row>>1)&3)
  const int r0 = tid >> 2,        c2s = tid & 3;
  const int r1 = (tid + 512) >> 2;
  const int sc0 = c2s ^ ((r0 >> 1) & 3);
  const int sc1 = c2s ^ ((r1 >> 1) & 3);
  const char* aG0 = qx + ((long long)tileM*256 + r0)*din + sc0*16;
  const char* aG1 = qx + ((long long)tileM*256 + r1)*din + sc1*16;
  const char* bG0 = qw + ((long long)tileN*256 + r0)*din + sc0*16;
  const char* bG1 = qw + ((long long)tileN*256 + r1)*din + sc1*16;
  const int ld0 = tid*16, ld1 = (tid+512)*16;   // linear LDS dests

  // ---- ds_read addressing (swizzled chunk) ----
  const int physo = (((lane >> 4) ^ ((lane >> 1) & 3)) * 16);
  const int arowL = wr*128 + (lane & 15);       // + MH*64 + mi*16
  const int browL = wc*64  + (lane & 15);       // + ni*16

  i32x4 acc[8][4] = {};
  const int nk = din / 64;

  // ---- prologue: stage tiles 0,1; wait tile 0; barrier ----
  {
    char* A0 = lds;               char* B0 = lds + 3*TILE_BYTES;
    char* A1 = lds + TILE_BYTES;  char* B1 = lds + 4*TILE_BYTES;
    gload16(aG0, A0 + ld0); gload16(aG1, A0 + ld1);
    gload16(bG0, B0 + ld0); gload16(bG1, B0 + ld1);
    gload16(aG0 + 64, A1 + ld0); gload16(aG1 + 64, A1 + ld1);
    gload16(bG0 + 64, B1 + ld0); gload16(bG1 + 64, B1 + ld1);
  }
  asm volatile("s_waitcnt vmcnt(4)" ::: "memory");
  __builtin_amdgcn_s_barrier();

  for(int kt = 0; kt < nk; ++kt){
    const int slot  = kt % 3;
    char* As = lds + slot*TILE_BYTES;
    char* Bs = lds + (3 + slot)*TILE_BYTES;
    const bool pref = (kt + 2 < nk);
    const int nslot = (kt + 2) % 3;
    const long long ko = (long long)(kt + 2) * 64;

    i32x4 a[4], b[4];
    // ---- phase 1: read B(all) + A(mh=0); issue A-stage; 16 MFMA ----
    #pragma unroll
    for(int ni=0; ni<4; ++ni) b[ni] = *(const i32x4*)(Bs + (browL + ni*16)*64 + physo);
    #pragma unroll
    for(int mi=0; mi<4; ++mi) a[mi] = *(const i32x4*)(As + (arowL + mi*16)*64 + physo);
    if(pref){
      char* An = lds + nslot*TILE_BYTES;
      gload16(aG0 + ko, An + ld0); gload16(aG1 + ko, An + ld1);
    }
    __builtin_amdgcn_s_barrier();
    __builtin_amdgcn_s_setprio(1);
    #pragma unroll
    for(int mi=0; mi<4; ++mi)
      #pragma unroll
      for(int ni=0; ni<4; ++ni)
        acc[mi][ni] = __builtin_amdgcn_mfma_i32_16x16x64_i8(a[mi], b[ni], acc[mi][ni], 0, 0, 0);
    __builtin_amdgcn_s_setprio(0);
    __builtin_amdgcn_s_barrier();

    // ---- phase 2: read A(mh=1); issue B-stage; 16 MFMA; boundary wait ----
    #pragma unroll
    for(int mi=0; mi<4; ++mi) a[mi] = *(const i32x4*)(As + (arowL + 64 + mi*16)*64 + physo);
    if(pref){
      char* Bn = lds + (3 + nslot)*TILE_BYTES;
      gload16(bG0 + ko, Bn + ld0); gload16(bG1 + ko, Bn + ld1);
    }
    __builtin_amdgcn_s_barrier();
    __builtin_amdgcn_s_setprio(1);
    #pragma unroll
    for(int mi=0; mi<4; ++mi)
      #pragma unroll
      for(int ni=0; ni<4; ++ni)
        acc[4+mi][ni] = __builtin_amdgcn_mfma_i32_16x16x64_i8(a[mi], b[ni], acc[4+mi][ni], 0, 0, 0);
    __builtin_amdgcn_s_setprio(0);
    if(kt < nk - 2) asm volatile("s_waitcnt vmcnt(4)" ::: "memory");
    else            asm volatile("s_waitcnt vmcnt(0)" ::: "memory");
    __builtin_amdgcn_s_barrier();
  }

  // ---- epilogue: out = ((acc + 128*sa + ci) + zp*sa) * (1/sx) * (1/sw) ----
  const float nm1 = (float)((1 << *wbit) - 1);
  const float xmaxc = fmaxf(__uint_as_float(*xmax_bits), 1e-8f);
  const float inv_sx = __fdiv_rn(xmaxc, nm1);
  const int colL = tileN*256 + wc*64 + (lane & 15);
  const int rowL = tileM*256 + wr*128 + ((lane >> 4) * 4);
  float invc[4], zp4[4]; int ci4[4];
  #pragma unroll
  for(int ni=0; ni<4; ++ni){
    int o = colL + ni*16;
    invc[ni] = __fmul_rn(winv[o], inv_sx);
    zp4[ni]  = zp_w[o];
    ci4[ni]  = cint[o];
  }
  #pragma unroll
  for(int mi=0; mi<8; ++mi){
    int rb = rowL + mi*16;
    int sav[4];
    #pragma unroll
    for(int r=0; r<4; ++r) sav[r] = Sa[rb + r];
    #pragma unroll
    for(int ni=0; ni<4; ++ni){
      #pragma unroll
      for(int r=0; r<4; ++r){
        int iv = acc[mi][ni][r] + 128*sav[r] + ci4[ni];
        float f = (float)iv + zp4[ni]*(float)sav[r];
        out[(long long)(rb + r)*dout + colL + ni*16] = __fmul_rn(f, invc[ni]);
      }
    }
  }
}

extern "C" void kernel_launch(void* const* d_in, const int* in_sizes, int n_in,
                              void* d_out, int out_size, void* d_ws, size_t ws_size,
                              hipStream_t stream){
  const float* x    = (const float*)d_in[0];
  const float* w    = (const float*)d_in[1];
  const float* bias = (const float*)d_in[2];
  const int*   wbit = (const int*)d_in[3];
  int dout = in_sizes[2];
  int din  = in_sizes[1] / dout;
  int T    = in_sizes[0] / din;

  const int NPART = 2048;
  char* ws = (char*)d_ws;
  uint32_t* xmax_bits = (uint32_t*)ws;
  size_t off = 256;
  float* partials = (float*)(ws + off); off += 4*(size_t)NPART;
  float* scale_w = (float*)(ws + off); off += 4*(size_t)dout;
  float* zp_w    = (float*)(ws + off); off += 4*(size_t)dout;
  float* winv    = (float*)(ws + off); off += 4*(size_t)dout;
  int*   cint    = (int*)(ws + off);   off += 4*(size_t)dout;
  int*   Sa      = (int*)(ws + off);   off += 4*(size_t)T;
  off = (off + 255) & ~(size_t)255;
  char*  qw      = ws + off;           off += (size_t)dout*din;
  char*  qx      = ws + off;           off += (size_t)T*din;

  long long n4 = (long long)T*din/4;
  k_xmax_partial<<<NPART, 256, 0, stream>>>(x, n4, partials);
  k_xmax_final<<<1, 256, 0, stream>>>(partials, NPART, xmax_bits);
  k_wstat<<<dout, 256, 0, stream>>>(w, bias, wbit, xmax_bits, scale_w, zp_w, winv, cint, qw, din);
  k_xquant<<<T, 256, 0, stream>>>(x, wbit, xmax_bits, qx, Sa, din);
  dim3 grid(dout/256, T/256);
  k_gemm<<<grid, 512, 6*TILE_BYTES, stream>>>(qx, qw, Sa, cint, winv, zp_w, wbit, xmax_bits,
                                              (float*)d_out, T, dout, din);
}